// Round 11
// baseline (437.704 us; speedup 1.0000x reference)
//
#include <hip/hip_runtime.h>
#include <hip/hip_bf16.h>

// ---------------- types ----------------
typedef __attribute__((ext_vector_type(8))) short s16x8;    // 8 bf16 in 4 VGPRs
typedef __attribute__((ext_vector_type(4))) float f32x4;

// B=4, C=256, H=W=160, padded spatial 162, S dims 161, N=512, REID=128

__device__ __forceinline__ void async_ld16(const void* g, void* l) {
  __builtin_amdgcn_global_load_lds(
      (const __attribute__((address_space(1))) void*)g,
      (__attribute__((address_space(3))) void*)l, 16, 0, 0);
}

// ---------------- 0. merged prep: NCHW->NHWC + borders + weight pack + bn fold + mlp transpose ---
// blocks [0,12800): nchw2nhwc (64ch x 32x tile, packed-pair writes); [12800,17952): borders;
// [17952,22560): pack_w; [22560,22562): prep_bn; [22562,22754): pack_mlp
__global__ __launch_bounds__(256) void prep_all(
    const float* __restrict__ x,
    __hip_bfloat16* __restrict__ xpad, __hip_bfloat16* __restrict__ f1,
    const float* __restrict__ cw, __hip_bfloat16* __restrict__ wpk,
    const float* __restrict__ cb, const float* __restrict__ g,
    const float* __restrict__ bt, const float* __restrict__ mn,
    const float* __restrict__ vr, float* __restrict__ ab,
    const float* __restrict__ w1, const float* __restrict__ w2,
    float* __restrict__ w1t, float* __restrict__ w2t) {
  __shared__ unsigned tile_u[32][33];  // [channel-pair][x] packed bf16x2; pad 33 -> conflict-free
  int bi = blockIdx.x;
  int t = threadIdx.x;
  if (bi < 12800) {
    int xt = bi % 5;
    int cq = (bi / 5) & 3;
    int by = bi / 20;
    int b = by / 160, y = by - (by / 160) * 160;
    // read: thread t -> channel pair p = t>>3 (0..31), x-quad q = t&7; float4 from 2 channels
    int p = t >> 3, q = t & 7;
    int c0 = cq * 64 + 2 * p;
    const float* row = x + (((size_t)(b * 256 + c0)) * 160 + y) * 160 + xt * 32 + q * 4;
    float4 v0 = *(const float4*)row;
    float4 v1 = *(const float4*)(row + 25600);  // channel c0+1
#pragma unroll
    for (int k = 0; k < 4; k++) {
      float vk0 = (&v0.x)[k], vk1 = (&v1.x)[k];
      __hip_bfloat16 lo = __float2bfloat16(vk0), hi = __float2bfloat16(vk1);
      tile_u[p][q * 4 + k] =
          (unsigned)*(unsigned short*)&lo | ((unsigned)*(unsigned short*)&hi << 16);
    }
    __syncthreads();
    // write: thread t -> pair s = t&31, x-lane xh = t>>5 (0..7); 4 x's per thread
    int s = t & 31, xh = t >> 5;
    unsigned* dstu = (unsigned*)xpad;
#pragma unroll
    for (int xr = 0; xr < 4; xr++) {
      int xx = xr * 8 + xh;
      size_t du = (((size_t)(b * 162 + y + 1)) * 162 + 1 + xt * 32 + xx) * 128 + cq * 32 + s;
      dstu[du] = tile_u[s][xx];
    }
  } else if (bi < 17952) {
    int e0 = bi - 12800;
    int buf = e0 / 2576; int rem = e0 - buf * 2576;
    int b = rem / 644;   int e = rem - b * 644;
    int y, xx;
    if (e < 162)      { y = 0;           xx = e; }
    else if (e < 324) { y = 161;         xx = e - 162; }
    else if (e < 484) { y = e - 324 + 1; xx = 0; }
    else              { y = e - 484 + 1; xx = 161; }
    __hip_bfloat16* p = (buf ? f1 : xpad) + (((size_t)b * 162 + y) * 162 + xx) * 256 + t;
    *p = __float2bfloat16(0.f);
  } else if (bi < 22560) {
    int tt = (bi - 17952) * 256 + t;
    int ci = tt & 255, co = (tt >> 8) & 255, rest = tt >> 16;
    int tap = rest % 9, lyr = rest / 9;
    int dy = tap / 3, dx = tap - dy * 3;
    float v = cw[((((size_t)lyr * 256 + co) * 256 + ci) * 3 + dy) * 3 + dx];
    wpk[(((size_t)lyr * 9 + tap) * 256 + co) * 256 + ci] = __float2bfloat16(v);
  } else if (bi < 22562) {
    int tt = (bi - 22560) * 256 + t;  // 512
    float a = g[tt] / sqrtf(vr[tt] + 1e-5f);
    ab[tt] = a;
    ab[512 + tt] = (cb[tt] - mn[tt]) * a + bt[tt];
  } else {
    int tt = (bi - 22562) * 256 + t;
    if (tt < 32768) {
      int h = tt >> 8, k = tt & 255;
      w1t[k * 128 + h] = w1[h * 256 + k];
    } else {
      int u = tt - 32768;
      int r = u >> 7, k = u & 127;
      w2t[k * 128 + r] = w2[r * 128 + k];
    }
  }
}

// ---------------- 4. conv3x3 + BN + ReLU, implicit GEMM (bf16 MFMA) — R8-proven structure -------
// BM=128, BN=256 (full N), BK=64; 4 waves, wave-tile 64x128 (4x8 frags of 16x16x32).
// 2-barrier K-step; LDS linear, XOR-swizzled via pre-swizzled global source; T1 XCD swizzle.
__global__ __launch_bounds__(256, 2) void conv_bn_relu(
    const __hip_bfloat16* __restrict__ inp, __hip_bfloat16* __restrict__ outp,
    const __hip_bfloat16* __restrict__ wpk,  // [9][256][256] (tap, co, ci)
    const float* __restrict__ alpha, const float* __restrict__ beff) {
  __shared__ __align__(16) short As[128 * 64];   // 16 KB
  __shared__ __align__(16) short Bs[256 * 64];   // 32 KB
  const int t = threadIdx.x;
  // T1: bijective XCD swizzle (grid 800 = 8*100)
  const int mtile = ((blockIdx.x & 7) * 100) + (blockIdx.x >> 3);  // 0..799
  const int l = t & 63;
  const int wv = t >> 6;
  const int lr = l & 15, lq = l >> 4;
  const int wm = wv >> 1, wn = wv & 1;  // wave-tile: rows wm*64.., cols wn*128..

  const int srow = t >> 3;                              // 0..31
  const int koff = (((t & 7) ^ (srow & 7)) << 3);       // logical k-offset (shorts)
  const short* inS = (const short*)inp;
  const short* wS = (const short*)wpk;
  long abase[4];
#pragma unroll
  for (int i = 0; i < 4; i++) {
    int p = mtile * 128 + i * 32 + srow;
    int b = p / 25600; int r = p - b * 25600; int y = r / 160; int x = r - y * 160;
    abase[i] = (((long)b * 162 + y) * 162 + x) * 256 + koff;
  }
  const long bbase = ((long)srow) * 256 + koff;  // + j*8192 for row group j

  f32x4 acc[4][8];
#pragma unroll
  for (int i = 0; i < 4; i++)
#pragma unroll
    for (int j = 0; j < 8; j++) acc[i][j] = (f32x4){0.f, 0.f, 0.f, 0.f};

#pragma unroll 1
  for (int u = 0; u < 36; ++u) {
    const int tap = u >> 2, kc = u & 3;
    const int dy = tap / 3, dx = tap - dy * 3;
    const long aoff = ((long)(dy * 162 + dx)) * 256 + kc * 64;
    const long boff = (long)tap * 65536 + kc * 64;
    __syncthreads();  // previous step's LDS reads done
#pragma unroll
    for (int i = 0; i < 4; i++)
      async_ld16(inS + abase[i] + aoff, As + i * 2048 + t * 8);
#pragma unroll
    for (int j = 0; j < 8; j++)
      async_ld16(wS + bbase + boff + (long)j * 8192, Bs + j * 2048 + t * 8);
    __syncthreads();  // drains vmcnt(0): tiles ready
#pragma unroll
    for (int kk = 0; kk < 2; ++kk) {
      const int ps = (((kk << 2) | lq) ^ (lr & 7)) << 3;  // swizzled slot (shorts)
      s16x8 av[4], bv[8];
#pragma unroll
      for (int mi = 0; mi < 4; ++mi)
        av[mi] = *(const s16x8*)&As[(wm * 64 + mi * 16 + lr) * 64 + ps];
#pragma unroll
      for (int ni = 0; ni < 8; ++ni)
        bv[ni] = *(const s16x8*)&Bs[(wn * 128 + ni * 16 + lr) * 64 + ps];
#pragma unroll
      for (int mi = 0; mi < 4; ++mi)
#pragma unroll
        for (int ni = 0; ni < 8; ++ni)
          acc[mi][ni] = __builtin_amdgcn_mfma_f32_16x16x32_bf16(av[mi], bv[ni], acc[mi][ni], 0, 0, 0);
    }
  }

  // epilogue: y = relu(acc*alpha + beff) -> bf16, padded NHWC
  float al[8], be_[8];
#pragma unroll
  for (int ni = 0; ni < 8; ++ni) {
    int co = wn * 128 + ni * 16 + lr;
    al[ni] = alpha[co];
    be_[ni] = beff[co];
  }
#pragma unroll
  for (int mi = 0; mi < 4; ++mi) {
    int prow = mtile * 128 + wm * 64 + mi * 16 + lq * 4;
#pragma unroll
    for (int j = 0; j < 4; ++j) {
      int p = prow + j;
      int b = p / 25600; int r = p - b * 25600; int y = r / 160; int x = r - y * 160;
      long ob = (((long)b * 162 + (y + 1)) * 162 + (x + 1)) * 256 + wn * 128;
#pragma unroll
      for (int ni = 0; ni < 8; ++ni) {
        float v = acc[mi][ni][j] * al[ni] + be_[ni];
        outp[ob + ni * 16 + lr] = __float2bfloat16(fmaxf(v, 0.f));
      }
    }
  }
}

// ---------------- 5. cumsum along W: bf16 f -> fp32 S, channel-pair vectorized, batch-8 ---------
__global__ __launch_bounds__(128) void cumsum_w(const __hip_bfloat16* __restrict__ f2,
                                                float* __restrict__ S) {
  int row = blockIdx.x;                            // 0..639
  int b = row / 160, y = row - (row / 160) * 160;
  int cp = threadIdx.x;                            // channel pair index
  const unsigned* src =
      (const unsigned*)((const short*)f2 + (((size_t)b * 162 + y + 1) * 162 + 1) * 256) + cp;
  float2* dst = (float2*)(S + (((size_t)b * 161 + y + 1) * 161) * 256) + cp;
  dst[0] = float2{0.f, 0.f};
  float r0 = 0.f, r1 = 0.f;
  for (int x8 = 0; x8 < 160; x8 += 8) {
    unsigned v[8];
#pragma unroll
    for (int k = 0; k < 8; k++) v[k] = src[(size_t)(x8 + k) * 128];
#pragma unroll
    for (int k = 0; k < 8; k++) {
      r0 += __uint_as_float((v[k] & 0xffffu) << 16);
      r1 += __uint_as_float(v[k] & 0xffff0000u);
      dst[(size_t)(x8 + k + 1) * 128] = float2{r0, r1};
    }
  }
}

// ---------------- 6. cumsum along H in place (16-deep load batching) ----------------
__global__ __launch_bounds__(256) void cumsum_h(float* __restrict__ S) {
  int bi = blockIdx.x;  // 4*161
  int b = bi / 161, q = bi - (bi / 161) * 161;
  int c = threadIdx.x;
  float* col = S + (((size_t)b * 161) * 161 + q) * 256 + c;
  const size_t ys = (size_t)161 * 256;
  col[0] = 0.f;
  float run = 0.f;
  for (int y0 = 1; y0 <= 160; y0 += 16) {
    float v[16];
#pragma unroll
    for (int k = 0; k < 16; k++) v[k] = col[(size_t)(y0 + k) * ys];
#pragma unroll
    for (int k = 0; k < 16; k++) { run += v[k]; col[(size_t)(y0 + k) * ys] = run; }
  }
}

// ---------------- 7. fused ROI pool + MLP + normalize, 2 boxes/block (weight reuse) -------------
// block 256 = 2 box-groups of 128 lanes; concurrent gather keeps memory parallelism.
__global__ __launch_bounds__(256) void roi_mlp(const float* __restrict__ S,
                                               const float* __restrict__ bbox,
                                               const float* __restrict__ w1t,
                                               const float* __restrict__ b1,
                                               const float* __restrict__ w2t,
                                               const float* __restrict__ b2,
                                               float* __restrict__ out) {
  int t = threadIdx.x;
  int box = t >> 7;                 // 0 or 1
  int bn = blockIdx.x * 2 + box;    // 0..2047
  int b = bn >> 9;
  __shared__ float pl[2][256];
  __shared__ float hh[2][128];
  __shared__ float red[2][2];

  // ---- geometry for THIS thread's box (wave-uniform: box fixed per 2-wave half) ----
  float bx1 = bbox[bn * 4 + 0], by1 = bbox[bn * 4 + 1];
  float bx2 = bbox[bn * 4 + 2], by2 = bbox[bn * 4 + 3];
  int x1 = min(max((int)floorf(bx1 * 160.f), 0), 160);
  int y1 = min(max((int)floorf(by1 * 160.f), 0), 160);
  int x2 = min(max((int)floorf(bx2 * 160.f), 0), 160);
  int y2 = min(max((int)floorf(by2 * 160.f), 0), 160);
  int vld = (x2 > x1 && y2 > y1) ? 1 : 0;
  int hl = max(y2 - y1, 1), wl = max(x2 - x1, 1);
  int hs[7], he[7], ws_[7], we_[7];
  float rh[7], rw[7];
#pragma unroll
  for (int i = 0; i < 7; i++) {
    hs[i] = y1 + (i * hl) / 7;
    he[i] = y1 + ((i + 1) * hl + 6) / 7;
    rh[i] = 1.f / (float)(he[i] - hs[i]);
    ws_[i] = x1 + (i * wl) / 7;
    we_[i] = x1 + ((i + 1) * wl + 6) / 7;
    rw[i] = 1.f / (float)(we_[i] - ws_[i]);
  }
  // ---- gather: 2 iterations cover 256 channels per box, both boxes concurrent ----
#pragma unroll
  for (int iter = 0; iter < 2; iter++) {
    int c = (t & 127) + iter * 128;
    const float* Sb = S + (size_t)b * 161 * 161 * 256 + c;
    float acc = 0.f;
#pragma unroll
    for (int i = 0; i < 7; i++) {
      const float* rE = Sb + (size_t)he[i] * (161 * 256);
      const float* rS = Sb + (size_t)hs[i] * (161 * 256);
#pragma unroll
      for (int j = 0; j < 7; j++) {
        size_t qe = (size_t)we_[j] * 256, qs = (size_t)ws_[j] * 256;
        float s = rE[qe] - rS[qe] - rE[qs] + rS[qs];
        acc += s * (rh[i] * rw[j]);
      }
    }
    pl[box][c] = acc * (1.f / 49.f);
  }
  __syncthreads();

  // ---- MLP layer 1: 2x128 tasks, 1/thread ----
  int unit = t & 127;
  float a = b1[unit];
#pragma unroll 8
  for (int k = 0; k < 256; k++) a += w1t[k * 128 + unit] * pl[box][k];
  hh[box][unit] = fmaxf(a, 0.f);
  __syncthreads();

  // ---- MLP layer 2 + mask + L2 normalize ----
  float f = b2[unit];
#pragma unroll 8
  for (int k = 0; k < 128; k++) f += w2t[k * 128 + unit] * hh[box][k];
  if (!vld) f = 0.f;
  float ss = f * f;
#pragma unroll
  for (int off = 32; off > 0; off >>= 1) ss += __shfl_xor(ss, off);
  if ((t & 63) == 0) red[box][(t >> 6) & 1] = ss;
  __syncthreads();
  float nrm = fmaxf(sqrtf(red[box][0] + red[box][1]), 1e-12f);
  out[(size_t)bn * 128 + unit] = f / nrm;
}

// ---------------- launch ----------------
extern "C" void kernel_launch(void* const* d_in, const int* in_sizes, int n_in,
                              void* d_out, int out_size, void* d_ws, size_t ws_size,
                              hipStream_t stream) {
  const float* x = (const float*)d_in[0];
  const float* bboxes = (const float*)d_in[1];
  const float* conv_w = (const float*)d_in[2];
  const float* conv_b = (const float*)d_in[3];
  const float* bn_g = (const float*)d_in[4];
  const float* bn_b = (const float*)d_in[5];
  const float* bn_m = (const float*)d_in[6];
  const float* bn_v = (const float*)d_in[7];
  const float* w1 = (const float*)d_in[8];
  const float* b1 = (const float*)d_in[9];
  const float* w2 = (const float*)d_in[10];
  const float* b2 = (const float*)d_in[11];

  char* ws = (char*)d_ws;
  const size_t PADB = (size_t)4 * 162 * 162 * 256 * 2;   // 53,747,712 B
  const size_t WPKB = (size_t)2 * 9 * 256 * 256 * 2;     // 2,359,296 B
  const size_t SB = (size_t)4 * 161 * 161 * 256 * 4;     // 106,172,416 B

  __hip_bfloat16* xpad = (__hip_bfloat16*)(ws);
  __hip_bfloat16* f1 = (__hip_bfloat16*)(ws + PADB);
  __hip_bfloat16* wpk = (__hip_bfloat16*)(ws + 2 * PADB);
  float* abuf = (float*)(ws + 2 * PADB + WPKB);
  float* S = (float*)(ws + 2 * PADB + WPKB + 4096);
  float* w1t = (float*)(ws + 2 * PADB + WPKB + 4096 + SB);
  float* w2t = w1t + 32768;

  prep_all<<<22754, 256, 0, stream>>>(x, xpad, f1, conv_w, wpk, conv_b, bn_g, bn_b, bn_m,
                                      bn_v, abuf, w1, w2, w1t, w2t);

  conv_bn_relu<<<800, 256, 0, stream>>>(xpad, f1, wpk, abuf, abuf + 512);
  conv_bn_relu<<<800, 256, 0, stream>>>(f1, xpad, wpk + (size_t)9 * 256 * 256, abuf + 256, abuf + 768);

  cumsum_w<<<640, 128, 0, stream>>>(xpad, S);
  cumsum_h<<<644, 256, 0, stream>>>(S);
  roi_mlp<<<1024, 256, 0, stream>>>(S, bboxes, w1t, b1, w2t, b2, (float*)d_out);
}

// Round 12
// 396.659 us; speedup vs baseline: 1.1035x; 1.1035x over previous
//
#include <hip/hip_runtime.h>
#include <hip/hip_bf16.h>

// ---------------- types ----------------
typedef __attribute__((ext_vector_type(8))) short s16x8;    // 8 bf16 in 4 VGPRs
typedef __attribute__((ext_vector_type(4))) float f32x4;

// B=4, C=256, H=W=160, padded spatial 162, S dims 161, N=512, REID=128

__device__ __forceinline__ void async_ld16(const void* g, void* l) {
  __builtin_amdgcn_global_load_lds(
      (const __attribute__((address_space(1))) void*)g,
      (__attribute__((address_space(3))) void*)l, 16, 0, 0);
}

// ---------------- 0. merged prep: NCHW->NHWC + borders + weight pack + bn fold + mlp transpose ---
// blocks [0,12800): nchw2nhwc (64ch x 32x tile, packed-pair writes); [12800,17952): borders;
// [17952,22560): pack_w; [22560,22562): prep_bn; [22562,22754): pack_mlp
__global__ __launch_bounds__(256) void prep_all(
    const float* __restrict__ x,
    __hip_bfloat16* __restrict__ xpad, __hip_bfloat16* __restrict__ f1,
    const float* __restrict__ cw, __hip_bfloat16* __restrict__ wpk,
    const float* __restrict__ cb, const float* __restrict__ g,
    const float* __restrict__ bt, const float* __restrict__ mn,
    const float* __restrict__ vr, float* __restrict__ ab,
    const float* __restrict__ w1, const float* __restrict__ w2,
    float* __restrict__ w1t, float* __restrict__ w2t) {
  __shared__ unsigned tile_u[32][33];  // [channel-pair][x] packed bf16x2; pad 33 -> conflict-free
  int bi = blockIdx.x;
  int t = threadIdx.x;
  if (bi < 12800) {
    int xt = bi % 5;
    int cq = (bi / 5) & 3;
    int by = bi / 20;
    int b = by / 160, y = by - (by / 160) * 160;
    // read: thread t -> channel pair p = t>>3 (0..31), x-quad q = t&7; float4 from 2 channels
    int p = t >> 3, q = t & 7;
    int c0 = cq * 64 + 2 * p;
    const float* row = x + (((size_t)(b * 256 + c0)) * 160 + y) * 160 + xt * 32 + q * 4;
    float4 v0 = *(const float4*)row;
    float4 v1 = *(const float4*)(row + 25600);  // channel c0+1
#pragma unroll
    for (int k = 0; k < 4; k++) {
      float vk0 = (&v0.x)[k], vk1 = (&v1.x)[k];
      __hip_bfloat16 lo = __float2bfloat16(vk0), hi = __float2bfloat16(vk1);
      tile_u[p][q * 4 + k] =
          (unsigned)*(unsigned short*)&lo | ((unsigned)*(unsigned short*)&hi << 16);
    }
    __syncthreads();
    // write: thread t -> pair s = t&31, x-lane xh = t>>5 (0..7); 4 x's per thread
    int s = t & 31, xh = t >> 5;
    unsigned* dstu = (unsigned*)xpad;
#pragma unroll
    for (int xr = 0; xr < 4; xr++) {
      int xx = xr * 8 + xh;
      size_t du = (((size_t)(b * 162 + y + 1)) * 162 + 1 + xt * 32 + xx) * 128 + cq * 32 + s;
      dstu[du] = tile_u[s][xx];
    }
  } else if (bi < 17952) {
    int e0 = bi - 12800;
    int buf = e0 / 2576; int rem = e0 - buf * 2576;
    int b = rem / 644;   int e = rem - b * 644;
    int y, xx;
    if (e < 162)      { y = 0;           xx = e; }
    else if (e < 324) { y = 161;         xx = e - 162; }
    else if (e < 484) { y = e - 324 + 1; xx = 0; }
    else              { y = e - 484 + 1; xx = 161; }
    __hip_bfloat16* p = (buf ? f1 : xpad) + (((size_t)b * 162 + y) * 162 + xx) * 256 + t;
    *p = __float2bfloat16(0.f);
  } else if (bi < 22560) {
    int tt = (bi - 17952) * 256 + t;
    int ci = tt & 255, co = (tt >> 8) & 255, rest = tt >> 16;
    int tap = rest % 9, lyr = rest / 9;
    int dy = tap / 3, dx = tap - dy * 3;
    float v = cw[((((size_t)lyr * 256 + co) * 256 + ci) * 3 + dy) * 3 + dx];
    wpk[(((size_t)lyr * 9 + tap) * 256 + co) * 256 + ci] = __float2bfloat16(v);
  } else if (bi < 22562) {
    int tt = (bi - 22560) * 256 + t;  // 512
    float a = g[tt] / sqrtf(vr[tt] + 1e-5f);
    ab[tt] = a;
    ab[512 + tt] = (cb[tt] - mn[tt]) * a + bt[tt];
  } else {
    int tt = (bi - 22562) * 256 + t;
    if (tt < 32768) {
      int h = tt >> 8, k = tt & 255;
      w1t[k * 128 + h] = w1[h * 256 + k];
    } else {
      int u = tt - 32768;
      int r = u >> 7, k = u & 127;
      w2t[k * 128 + r] = w2[r * 128 + k];
    }
  }
}

// ---------------- 4. conv3x3 + BN + ReLU, implicit GEMM (bf16 MFMA) — R8-proven structure -------
// BM=128, BN=256 (full N), BK=64; 4 waves, wave-tile 64x128 (4x8 frags of 16x16x32).
// 2-barrier K-step; LDS linear, XOR-swizzled via pre-swizzled global source; T1 XCD swizzle.
__global__ __launch_bounds__(256, 2) void conv_bn_relu(
    const __hip_bfloat16* __restrict__ inp, __hip_bfloat16* __restrict__ outp,
    const __hip_bfloat16* __restrict__ wpk,  // [9][256][256] (tap, co, ci)
    const float* __restrict__ alpha, const float* __restrict__ beff) {
  __shared__ __align__(16) short As[128 * 64];   // 16 KB
  __shared__ __align__(16) short Bs[256 * 64];   // 32 KB
  const int t = threadIdx.x;
  // T1: bijective XCD swizzle (grid 800 = 8*100)
  const int mtile = ((blockIdx.x & 7) * 100) + (blockIdx.x >> 3);  // 0..799
  const int l = t & 63;
  const int wv = t >> 6;
  const int lr = l & 15, lq = l >> 4;
  const int wm = wv >> 1, wn = wv & 1;  // wave-tile: rows wm*64.., cols wn*128..

  const int srow = t >> 3;                              // 0..31
  const int koff = (((t & 7) ^ (srow & 7)) << 3);       // logical k-offset (shorts)
  const short* inS = (const short*)inp;
  const short* wS = (const short*)wpk;
  long abase[4];
#pragma unroll
  for (int i = 0; i < 4; i++) {
    int p = mtile * 128 + i * 32 + srow;
    int b = p / 25600; int r = p - b * 25600; int y = r / 160; int x = r - y * 160;
    abase[i] = (((long)b * 162 + y) * 162 + x) * 256 + koff;
  }
  const long bbase = ((long)srow) * 256 + koff;  // + j*8192 for row group j

  f32x4 acc[4][8];
#pragma unroll
  for (int i = 0; i < 4; i++)
#pragma unroll
    for (int j = 0; j < 8; j++) acc[i][j] = (f32x4){0.f, 0.f, 0.f, 0.f};

#pragma unroll 1
  for (int u = 0; u < 36; ++u) {
    const int tap = u >> 2, kc = u & 3;
    const int dy = tap / 3, dx = tap - dy * 3;
    const long aoff = ((long)(dy * 162 + dx)) * 256 + kc * 64;
    const long boff = (long)tap * 65536 + kc * 64;
    __syncthreads();  // previous step's LDS reads done
#pragma unroll
    for (int i = 0; i < 4; i++)
      async_ld16(inS + abase[i] + aoff, As + i * 2048 + t * 8);
#pragma unroll
    for (int j = 0; j < 8; j++)
      async_ld16(wS + bbase + boff + (long)j * 8192, Bs + j * 2048 + t * 8);
    __syncthreads();  // drains vmcnt(0): tiles ready
#pragma unroll
    for (int kk = 0; kk < 2; ++kk) {
      const int ps = (((kk << 2) | lq) ^ (lr & 7)) << 3;  // swizzled slot (shorts)
      s16x8 av[4], bv[8];
#pragma unroll
      for (int mi = 0; mi < 4; ++mi)
        av[mi] = *(const s16x8*)&As[(wm * 64 + mi * 16 + lr) * 64 + ps];
#pragma unroll
      for (int ni = 0; ni < 8; ++ni)
        bv[ni] = *(const s16x8*)&Bs[(wn * 128 + ni * 16 + lr) * 64 + ps];
#pragma unroll
      for (int mi = 0; mi < 4; ++mi)
#pragma unroll
        for (int ni = 0; ni < 8; ++ni)
          acc[mi][ni] = __builtin_amdgcn_mfma_f32_16x16x32_bf16(av[mi], bv[ni], acc[mi][ni], 0, 0, 0);
    }
  }

  // epilogue: y = relu(acc*alpha + beff) -> bf16, padded NHWC
  float al[8], be_[8];
#pragma unroll
  for (int ni = 0; ni < 8; ++ni) {
    int co = wn * 128 + ni * 16 + lr;
    al[ni] = alpha[co];
    be_[ni] = beff[co];
  }
#pragma unroll
  for (int mi = 0; mi < 4; ++mi) {
    int prow = mtile * 128 + wm * 64 + mi * 16 + lq * 4;
#pragma unroll
    for (int j = 0; j < 4; ++j) {
      int p = prow + j;
      int b = p / 25600; int r = p - b * 25600; int y = r / 160; int x = r - y * 160;
      long ob = (((long)b * 162 + (y + 1)) * 162 + (x + 1)) * 256 + wn * 128;
#pragma unroll
      for (int ni = 0; ni < 8; ++ni) {
        float v = acc[mi][ni][j] * al[ni] + be_[ni];
        outp[ob + ni * 16 + lr] = __float2bfloat16(fmaxf(v, 0.f));
      }
    }
  }
}

// ---------------- 5. cumsum along W: bf16 f -> fp32 S, channel-pair vectorized, batch-8 ---------
__global__ __launch_bounds__(128) void cumsum_w(const __hip_bfloat16* __restrict__ f2,
                                                float* __restrict__ S) {
  int row = blockIdx.x;                            // 0..639
  int b = row / 160, y = row - (row / 160) * 160;
  int cp = threadIdx.x;                            // channel pair index
  const unsigned* src =
      (const unsigned*)((const short*)f2 + (((size_t)b * 162 + y + 1) * 162 + 1) * 256) + cp;
  float2* dst = (float2*)(S + (((size_t)b * 161 + y + 1) * 161) * 256) + cp;
  dst[0] = float2{0.f, 0.f};
  float r0 = 0.f, r1 = 0.f;
  for (int x8 = 0; x8 < 160; x8 += 8) {
    unsigned v[8];
#pragma unroll
    for (int k = 0; k < 8; k++) v[k] = src[(size_t)(x8 + k) * 128];
#pragma unroll
    for (int k = 0; k < 8; k++) {
      r0 += __uint_as_float((v[k] & 0xffffu) << 16);
      r1 += __uint_as_float(v[k] & 0xffff0000u);
      dst[(size_t)(x8 + k + 1) * 128] = float2{r0, r1};
    }
  }
}

// ---------------- 6. cumsum along H in place (16-deep load batching) ----------------
__global__ __launch_bounds__(256) void cumsum_h(float* __restrict__ S) {
  int bi = blockIdx.x;  // 4*161
  int b = bi / 161, q = bi - (bi / 161) * 161;
  int c = threadIdx.x;
  float* col = S + (((size_t)b * 161) * 161 + q) * 256 + c;
  const size_t ys = (size_t)161 * 256;
  col[0] = 0.f;
  float run = 0.f;
  for (int y0 = 1; y0 <= 160; y0 += 16) {
    float v[16];
#pragma unroll
    for (int k = 0; k < 16; k++) v[k] = col[(size_t)(y0 + k) * ys];
#pragma unroll
    for (int k = 0; k < 16; k++) { run += v[k]; col[(size_t)(y0 + k) * ys] = run; }
  }
}

// ---------------- 7. fused ROI pool + MLP + normalize: 512 thr / 2 boxes (full TLP + wt reuse) --
// grid 1024; waves/CU identical to the 2048x256 version (32), weights read once per 2 boxes.
__global__ __launch_bounds__(512) void roi_mlp(const float* __restrict__ S,
                                               const float* __restrict__ bbox,
                                               const float* __restrict__ w1t,
                                               const float* __restrict__ b1,
                                               const float* __restrict__ w2t,
                                               const float* __restrict__ b2,
                                               float* __restrict__ out) {
  int t = threadIdx.x;
  int box = t >> 8;                 // 0 or 1 (wave-uniform)
  int bn = blockIdx.x * 2 + box;    // 0..2047
  int b = bn >> 9;
  __shared__ float pl[2][256];
  __shared__ float hh[2][128];
  __shared__ float red[2][2];

  float bx1 = bbox[bn * 4 + 0], by1 = bbox[bn * 4 + 1];
  float bx2 = bbox[bn * 4 + 2], by2 = bbox[bn * 4 + 3];
  int x1 = min(max((int)floorf(bx1 * 160.f), 0), 160);
  int y1 = min(max((int)floorf(by1 * 160.f), 0), 160);
  int x2 = min(max((int)floorf(bx2 * 160.f), 0), 160);
  int y2 = min(max((int)floorf(by2 * 160.f), 0), 160);
  int vld = (x2 > x1 && y2 > y1) ? 1 : 0;
  int hl = max(y2 - y1, 1), wl = max(x2 - x1, 1);
  int hs[7], he[7], ws_[7], we_[7];
  float rh[7], rw[7];
#pragma unroll
  for (int i = 0; i < 7; i++) {
    hs[i] = y1 + (i * hl) / 7;
    he[i] = y1 + ((i + 1) * hl + 6) / 7;
    rh[i] = 1.f / (float)(he[i] - hs[i]);
    ws_[i] = x1 + (i * wl) / 7;
    we_[i] = x1 + ((i + 1) * wl + 6) / 7;
    rw[i] = 1.f / (float)(we_[i] - ws_[i]);
  }
  // gather: one channel per lane (256 lanes per box), same per-thread work as 1-box version
  int c = t & 255;
  const float* Sb = S + (size_t)b * 161 * 161 * 256 + c;
  float acc = 0.f;
#pragma unroll
  for (int i = 0; i < 7; i++) {
    const float* rE = Sb + (size_t)he[i] * (161 * 256);
    const float* rS = Sb + (size_t)hs[i] * (161 * 256);
#pragma unroll
    for (int j = 0; j < 7; j++) {
      size_t qe = (size_t)we_[j] * 256, qs = (size_t)ws_[j] * 256;
      float s = rE[qe] - rS[qe] - rE[qs] + rS[qs];
      acc += s * (rh[i] * rw[j]);
    }
  }
  pl[box][c] = acc * (1.f / 49.f);
  __syncthreads();

  int unit = t & 127;
  int half = (t >> 7) & 1;  // first 128 lanes of each box group do the MLP
  float f = 0.f;
  if (half == 0) {
    float a = b1[unit];
#pragma unroll 8
    for (int k = 0; k < 256; k++) a += w1t[k * 128 + unit] * pl[box][k];
    hh[box][unit] = fmaxf(a, 0.f);
  }
  __syncthreads();
  if (half == 0) {
    f = b2[unit];
#pragma unroll 8
    for (int k = 0; k < 128; k++) f += w2t[k * 128 + unit] * hh[box][k];
    if (!vld) f = 0.f;
    float ss = f * f;
#pragma unroll
    for (int off = 32; off > 0; off >>= 1) ss += __shfl_xor(ss, off);
    if ((t & 63) == 0) red[box][(t >> 6) & 1] = ss;
  }
  __syncthreads();
  if (half == 0) {
    float nrm = fmaxf(sqrtf(red[box][0] + red[box][1]), 1e-12f);
    out[(size_t)bn * 128 + unit] = f / nrm;
  }
}

// ---------------- launch ----------------
extern "C" void kernel_launch(void* const* d_in, const int* in_sizes, int n_in,
                              void* d_out, int out_size, void* d_ws, size_t ws_size,
                              hipStream_t stream) {
  const float* x = (const float*)d_in[0];
  const float* bboxes = (const float*)d_in[1];
  const float* conv_w = (const float*)d_in[2];
  const float* conv_b = (const float*)d_in[3];
  const float* bn_g = (const float*)d_in[4];
  const float* bn_b = (const float*)d_in[5];
  const float* bn_m = (const float*)d_in[6];
  const float* bn_v = (const float*)d_in[7];
  const float* w1 = (const float*)d_in[8];
  const float* b1 = (const float*)d_in[9];
  const float* w2 = (const float*)d_in[10];
  const float* b2 = (const float*)d_in[11];

  char* ws = (char*)d_ws;
  const size_t PADB = (size_t)4 * 162 * 162 * 256 * 2;   // 53,747,712 B
  const size_t WPKB = (size_t)2 * 9 * 256 * 256 * 2;     // 2,359,296 B
  const size_t SB = (size_t)4 * 161 * 161 * 256 * 4;     // 106,172,416 B

  __hip_bfloat16* xpad = (__hip_bfloat16*)(ws);
  __hip_bfloat16* f1 = (__hip_bfloat16*)(ws + PADB);
  __hip_bfloat16* wpk = (__hip_bfloat16*)(ws + 2 * PADB);
  float* abuf = (float*)(ws + 2 * PADB + WPKB);
  float* S = (float*)(ws + 2 * PADB + WPKB + 4096);
  float* w1t = (float*)(ws + 2 * PADB + WPKB + 4096 + SB);
  float* w2t = w1t + 32768;

  prep_all<<<22754, 256, 0, stream>>>(x, xpad, f1, conv_w, wpk, conv_b, bn_g, bn_b, bn_m,
                                      bn_v, abuf, w1, w2, w1t, w2t);

  conv_bn_relu<<<800, 256, 0, stream>>>(xpad, f1, wpk, abuf, abuf + 512);
  conv_bn_relu<<<800, 256, 0, stream>>>(f1, xpad, wpk + (size_t)9 * 256 * 256, abuf + 256, abuf + 768);

  cumsum_w<<<640, 128, 0, stream>>>(xpad, S);
  cumsum_h<<<644, 256, 0, stream>>>(S);
  roi_mlp<<<1024, 512, 0, stream>>>(S, bboxes, w1t, b1, w2t, b2, (float*)d_out);
}